// Round 10
// baseline (85.691 us; speedup 1.0000x reference)
//
#include <hip/hip_runtime.h>

typedef unsigned short u16;
typedef unsigned int u32;
typedef float f32x4 __attribute__((ext_vector_type(4)));
typedef short s16x8 __attribute__((ext_vector_type(8)));
typedef unsigned int u32x2 __attribute__((ext_vector_type(2)));
typedef unsigned int u32x4 __attribute__((ext_vector_type(4)));

#define NB 4
#define NT 4096
#define ND 128
#define NQ (NB * NT)

// (1/sqrt(128)) * log2(e)  -- folded into Q so softmax runs in exp2 domain
#define QK_SCALE 0.12751879523138906f

using as3_void = __attribute__((address_space(3))) void;
using as1_void = __attribute__((address_space(1))) void;

__device__ __forceinline__ u16 f2bf(float x){
  unsigned u = __float_as_uint(x);
  return (u16)((u + 0x7FFFu + ((u >> 16) & 1u)) >> 16);   // RNE
}
__device__ __forceinline__ u32 cvtpk(float lo, float hi){
  u32 r; asm("v_cvt_pk_bf16_f32 %0, %1, %2" : "=v"(r) : "v"(lo), "v"(hi)); return r;
}
__device__ __forceinline__ f32x4 mfma16(s16x8 a, s16x8 b, f32x4 c){
  return __builtin_amdgcn_mfma_f32_16x16x32_bf16(a, b, c, 0, 0, 0);
}

// ---------------- kernel 0: weights -> bf16, transposed wt[mat][f][c] ----------------
__global__ void k_wprep(const float* __restrict__ Wq, const float* __restrict__ Wk,
                        const float* __restrict__ Wv, u16* __restrict__ WT){
  int mat = blockIdx.x >> 7;
  int f   = blockIdx.x & 127;
  const float* W = (mat == 0) ? Wq : (mat == 1) ? Wk : Wv;
  int c = threadIdx.x;
  WT[mat * 16384 + f * 128 + c] = f2bf(W[c * 128 + f]);
}

// ---------------- kernel 1: QKV projection (R8-verified layouts) ----------------
// Qs : bf16 [NQ][128], scaled by QK_SCALE (row-major)
// Ks : bf16 [NQ][128], element (r,f) at col f ^ ((r&7)<<3)                 (b128-read swizzle)
// VTs: bf16 [B][128][N], (f,n) at col n ^ ((f&3)<<3) ^ (((f>>2)&1)<<2)     (b64-read swizzle)
__global__ __launch_bounds__(256) void k_proj(
    const float* __restrict__ X, const u16* __restrict__ WT,
    const float* __restrict__ bq, const float* __restrict__ bk, const float* __restrict__ bv,
    u16* __restrict__ Qs, u16* __restrict__ Ks, u16* __restrict__ VTs)
{
  const int lane = threadIdx.x & 63;
  const int w    = threadIdx.x >> 6;
  const int lm = lane & 15, lg = lane >> 4;
  const int rowbase = blockIdx.x * 64 + w * 16;

  s16x8 a[4];
  const float* xr = X + (rowbase + lm) * ND;
  #pragma unroll
  for (int kc = 0; kc < 4; ++kc){
    f32x4 x0 = *(const f32x4*)(xr + kc * 32 + lg * 8);
    f32x4 x1 = *(const f32x4*)(xr + kc * 32 + lg * 8 + 4);
    s16x8 t;
    t[0]=(short)f2bf(x0[0]); t[1]=(short)f2bf(x0[1]); t[2]=(short)f2bf(x0[2]); t[3]=(short)f2bf(x0[3]);
    t[4]=(short)f2bf(x1[0]); t[5]=(short)f2bf(x1[1]); t[6]=(short)f2bf(x1[2]); t[7]=(short)f2bf(x1[3]);
    a[kc] = t;
  }

  #pragma unroll
  for (int mat = 0; mat < 3; ++mat){
    const float* bias = (mat==0) ? bq : (mat==1) ? bk : bv;
    float bl[8];
    #pragma unroll
    for (int n = 0; n < 8; ++n) bl[n] = bias[n * 16 + lm];
    f32x4 acc[8];
    #pragma unroll
    for (int n = 0; n < 8; ++n) acc[n] = f32x4{0.f,0.f,0.f,0.f};
    #pragma unroll
    for (int kc = 0; kc < 4; ++kc){
      #pragma unroll
      for (int n = 0; n < 8; ++n){
        s16x8 bf = *(const s16x8*)&WT[mat*16384 + (n*16 + lm)*128 + kc*32 + lg*8];
        acc[n] = mfma16(a[kc], bf, acc[n]);
      }
    }
    #pragma unroll
    for (int n = 0; n < 8; ++n){
      int f = n * 16 + lm;
      #pragma unroll
      for (int i = 0; i < 4; ++i){
        int r = rowbase + lg * 4 + i;
        float val = acc[n][i] + bl[n];
        if (mat == 0){
          Qs[r * ND + f] = f2bf(val * QK_SCALE);
        } else if (mat == 1){
          Ks[r * ND + (f ^ ((r & 7) << 3))] = f2bf(val);
        } else {
          int bb = r >> 12, nt = r & (NT - 1);
          VTs[(bb * ND + f) * NT + (nt ^ ((f & 3) << 3) ^ (((f >> 2) & 1) << 2))] = f2bf(val);
        }
      }
    }
  }
}

// ---------------- kernel 2: flash attention, T4 counted-vmcnt pipeline ----------
// 256 blocks = 2 halves x 128 qblocks(128 q). 8 waves = 4 qw (32 q, sq=2) x 2 g (1024 kv,
// 32 tiles of 32). 3-buffer staging, 2-deep prefetch, one raw s_barrier per tile,
// s_waitcnt vmcnt(4) counted (never drain in loop). Inner maps identical to R8.
__global__ __launch_bounds__(512, 2) void k_attn(
    const u16* __restrict__ Qs, const u16* __restrict__ Ks,
    const u16* __restrict__ VTs, float* __restrict__ Op, float* __restrict__ lp)
{
  __shared__ __align__(16) u16 lds[49152];          // 96 KiB: kbuf 3x2x4096 + vbuf same
  __shared__ float lbuf[4][32];                     // l merge (g1 -> g0)
  u16* kbuf = lds;                                  // [buf][g][32*128]
  u16* vbuf = lds + 24576;                          // [buf][g][128*32]

  // XCD-chunked: xcd gets 32 consecutive qblks of one half (~3 MB footprint/XCD L2)
  const int lin = blockIdx.x;
  const int logical = (lin & 7) * 32 + (lin >> 3);
  const int qblk = logical & 127;
  const int half = logical >> 7;

  const int lane = threadIdx.x & 63;
  const int w  = threadIdx.x >> 6;
  const int g  = w & 1, qw = w >> 1;                // 2 kv-groups, 4 q-waves
  const int lm = lane & 15, lg = lane >> 4;
  const int q0 = qblk * 128 + qw * 32;              // global q base for this wave
  const int b  = q0 >> 12;                          // batch
  const int kv0 = half * 2048 + g * 1024;

  // Q frags in registers: rows q0 + sq*16 + lm, k = kc*32 + lg*8 + j  (R8 map)
  s16x8 aq[2][4];
  #pragma unroll
  for (int sq = 0; sq < 2; ++sq){
    const u16* qr = Qs + (size_t)(q0 + sq * 16 + lm) * ND;
    #pragma unroll
    for (int kc = 0; kc < 4; ++kc) aq[sq][kc] = *(const s16x8*)(qr + kc * 32 + lg * 8);
  }

  f32x4 o[2][8];
  #pragma unroll
  for (int sq = 0; sq < 2; ++sq)
    #pragma unroll
    for (int n = 0; n < 8; ++n) o[sq][n] = f32x4{0.f,0.f,0.f,0.f};
  float l_[2] = {0.f, 0.f};

  // staging: the 4 qw waves split each group-tile; this wave does 2 K + 2 V chunks.
  // K chunk rows qw*8 + j*4 + (lane>>4); V chunk f-rows qw*32 + j*16 + (lane>>2).
  const u16* gk = Ks  + ((size_t)b * NT + kv0 + qw * 8 + (lane >> 4)) * ND + (lane & 15) * 8;
  const u16* gv = VTs + ((size_t)b * ND + qw * 32 + (lane >> 2)) * NT + kv0 + (lane & 3) * 8;

  auto stage = [&](int buf){
    u16* kd = kbuf + (buf * 2 + g) * 4096 + qw * 1024;
    u16* vd = vbuf + (buf * 2 + g) * 4096 + qw * 1024;
    __builtin_amdgcn_global_load_lds((const as1_void*)gk,
                                     (as3_void*)kd, 16, 0, 0);
    __builtin_amdgcn_global_load_lds((const as1_void*)(gk + (size_t)4 * ND),
                                     (as3_void*)(kd + 512), 16, 0, 0);
    __builtin_amdgcn_global_load_lds((const as1_void*)gv,
                                     (as3_void*)vd, 16, 0, 0);
    __builtin_amdgcn_global_load_lds((const as1_void*)(gv + (size_t)16 * NT),
                                     (as3_void*)(vd + 512), 16, 0, 0);
    gk += (size_t)32 * ND;
    gv += 32;
  };

  const int kswz = (lm & 7) << 3;                           // K b128-read swizzle
  const int vswz = ((lm & 3) << 3) ^ (((lm >> 2) & 1) << 2);// V b64-read swizzle
  const int vcol0 = (lg * 4) ^ vswz;                        // kv lg*4 + {0..3}
  const int vcol1 = (16 + lg * 4) ^ vswz;                   // kv 16+lg*4 + {0..3}

  stage(0);                        // tile 0 -> buf 0
  stage(1);                        // tile 1 -> buf 1
  int bufr = 0, bufs = 2;          // read buf = t%3, stage buf = (t+2)%3

  for (int t = 0; t < 32; ++t){
    // counted wait: ensure stage(t) landed; allow stage(t+1)'s 4 calls in flight
    if (t < 31) asm volatile("s_waitcnt vmcnt(4)" ::: "memory");
    else        asm volatile("s_waitcnt vmcnt(0)" ::: "memory");
    __builtin_amdgcn_sched_barrier(0);
    __builtin_amdgcn_s_barrier();            // all waves: buf[t%3] fully staged
    __builtin_amdgcn_sched_barrier(0);

    if (t < 30){                             // 2-deep prefetch into buf[(t+2)%3]
      stage(bufs);
      bufs = (bufs == 2) ? 0 : bufs + 1;
    }

    const u16* kb = kbuf + (bufr * 2 + g) * 4096;
    const u16* vb = vbuf + (bufr * 2 + g) * 4096;

    // ---- S^T = K Q : swapped operands; kf shared across sq ----
    f32x4 st[2][2];
    #pragma unroll
    for (int sq = 0; sq < 2; ++sq)
      #pragma unroll
      for (int n = 0; n < 2; ++n) st[sq][n] = f32x4{0.f,0.f,0.f,0.f};
    __builtin_amdgcn_s_setprio(1);
    #pragma unroll
    for (int kc = 0; kc < 4; ++kc){
      #pragma unroll
      for (int n = 0; n < 2; ++n){
        s16x8 kf = *(const s16x8*)&kb[(n * 16 + lm) * 128 + ((kc * 32 + lg * 8) ^ kswz)];
        st[0][n] = mfma16(kf, aq[0][kc], st[0][n]);
        st[1][n] = mfma16(kf, aq[1][kc], st[1][n]);
      }
    }
    __builtin_amdgcn_s_setprio(0);

    // ---- fixed-ref softmax in registers; pack PV A-frags (R8 bijection) ----
    s16x8 pa[2];
    #pragma unroll
    for (int sq = 0; sq < 2; ++sq){
      float p[8];
      #pragma unroll
      for (int n = 0; n < 2; ++n)
        #pragma unroll
        for (int i = 0; i < 4; ++i){
          p[n * 4 + i] = __builtin_amdgcn_exp2f(st[sq][n][i]);
          l_[sq] += p[n * 4 + i];
        }
      pa[sq] = __builtin_bit_cast(s16x8, u32x4{
          cvtpk(p[0], p[1]), cvtpk(p[2], p[3]),
          cvtpk(p[4], p[5]), cvtpk(p[6], p[7])});
    }

    // ---- O += P V : vf = 2x b64 (R8 map); shared across sq ----
    __builtin_amdgcn_s_setprio(1);
    #pragma unroll
    for (int nf = 0; nf < 8; ++nf){
      const int vr = (nf * 16 + lm) * 32;
      u32x2 v0 = *(const u32x2*)&vb[vr + vcol0];
      u32x2 v1 = *(const u32x2*)&vb[vr + vcol1];
      s16x8 vf = __builtin_bit_cast(s16x8, u32x4{v0[0], v0[1], v1[0], v1[1]});
      o[0][nf] = mfma16(pa[0], vf, o[0][nf]);
      o[1][nf] = mfma16(pa[1], vf, o[1][nf]);
    }
    __builtin_amdgcn_s_setprio(0);

    bufr = (bufr == 2) ? 0 : bufr + 1;
    // no end-of-tile barrier, no drain: next tile's vmcnt(4)+s_barrier covers it
  }

  // ---- l: reduce over lg (lanes sharing q) ----
  #pragma unroll
  for (int sq = 0; sq < 2; ++sq){
    float v = l_[sq];
    v += __shfl_xor(v, 16);
    v += __shfl_xor(v, 32);
    l_[sq] = v;                       // all lanes: l for q = sq*16+lm (this g)
  }

  // ---- merge g1 -> g0 via LDS; write f32 partials for this half ----
  float* mbF = (float*)lds;           // [4 qw][32 q][128 f] f32 = 64 KiB
  __syncthreads();                    // full drain once (end of compute)
  if (g == 1){
    #pragma unroll
    for (int sq = 0; sq < 2; ++sq){
      #pragma unroll
      for (int i = 0; i < 4; ++i)
        #pragma unroll
        for (int nf = 0; nf < 8; ++nf)
          mbF[qw * 4096 + (sq * 16 + lg * 4 + i) * 128 + nf * 16 + lm] = o[sq][nf][i];
      if (lg == 0) lbuf[qw][sq * 16 + lm] = l_[sq];
    }
  }
  __syncthreads();
  if (g == 0){
    #pragma unroll
    for (int sq = 0; sq < 2; ++sq){
      l_[sq] += lbuf[qw][sq * 16 + lm];
      #pragma unroll
      for (int i = 0; i < 4; ++i){
        const size_t r = (size_t)half * NQ + q0 + sq * 16 + lg * 4 + i;
        #pragma unroll
        for (int nf = 0; nf < 8; ++nf)
          Op[r * ND + nf * 16 + lm] =
              o[sq][nf][i] + mbF[qw * 4096 + (sq * 16 + lg * 4 + i) * 128 + nf * 16 + lm];
      }
      if (lg == 0) lp[(size_t)half * NQ + q0 + sq * 16 + lm] = l_[sq];
    }
  }
}

// ---------------- kernel 3: merge kv-halves + normalize ----------------
__global__ __launch_bounds__(256) void k_merge(const float* __restrict__ Op,
                                               const float* __restrict__ lp,
                                               float* __restrict__ Out){
  const int gid = blockIdx.x * 256 + threadIdx.x;   // over NQ*32 float4 chunks
  const int q = gid >> 5, c = gid & 31;
  f32x4 a = *(const f32x4*)(Op + (size_t)q * ND + c * 4);
  f32x4 d = *(const f32x4*)(Op + ((size_t)NQ + q) * ND + c * 4);
  const float inv = 1.f / (lp[q] + lp[NQ + q]);
  f32x4 r;
  r[0] = (a[0] + d[0]) * inv; r[1] = (a[1] + d[1]) * inv;
  r[2] = (a[2] + d[2]) * inv; r[3] = (a[3] + d[3]) * inv;
  *(f32x4*)(Out + (size_t)q * ND + c * 4) = r;
}

extern "C" void kernel_launch(void* const* d_in, const int* in_sizes, int n_in,
                              void* d_out, int out_size, void* d_ws, size_t ws_size,
                              hipStream_t stream) {
  const float* X  = (const float*)d_in[0];
  const float* Wq = (const float*)d_in[1];
  const float* bq = (const float*)d_in[2];
  const float* Wk = (const float*)d_in[3];
  const float* bk = (const float*)d_in[4];
  const float* Wv = (const float*)d_in[5];
  const float* bv = (const float*)d_in[6];
  float* Out = (float*)d_out;

  u16* Qs  = (u16*)d_ws;                        // 4 MiB
  u16* Ks  = Qs  + (size_t)NQ * ND;             // 4 MiB
  u16* VTs = Ks  + (size_t)NQ * ND;             // 4 MiB
  u16* WT  = VTs + (size_t)NQ * ND;             // 96 KiB
  float* Op = (float*)(WT + 3 * 128 * 128);     // 16 MiB  (2 halves)
  float* lp = Op + (size_t)2 * NQ * ND;         // 128 KiB

  hipLaunchKernelGGL(k_wprep, dim3(3 * 128), dim3(128), 0, stream, Wq, Wk, Wv, WT);
  hipLaunchKernelGGL(k_proj,  dim3(NQ / 64), dim3(256), 0, stream,
                     X, WT, bq, bk, bv, Qs, Ks, VTs);
  hipLaunchKernelGGL(k_attn,  dim3(256), dim3(512), 0, stream, Qs, Ks, VTs, Op, lp);
  hipLaunchKernelGGL(k_merge, dim3(NQ * 32 / 256), dim3(256), 0, stream, Op, lp, Out);
}

// Round 11
// 80.927 us; speedup vs baseline: 1.0589x; 1.0589x over previous
//
#include <hip/hip_runtime.h>

typedef unsigned short u16;
typedef unsigned int u32;
typedef float f32x4 __attribute__((ext_vector_type(4)));
typedef short s16x8 __attribute__((ext_vector_type(8)));
typedef unsigned int u32x2 __attribute__((ext_vector_type(2)));
typedef unsigned int u32x4 __attribute__((ext_vector_type(4)));

#define NB 4
#define NT 4096
#define ND 128
#define NQ (NB * NT)

// (1/sqrt(128)) * log2(e)  -- folded into Q so softmax runs in exp2 domain
#define QK_SCALE 0.12751879523138906f

using as3_void = __attribute__((address_space(3))) void;
using as1_void = __attribute__((address_space(1))) void;

__device__ __forceinline__ u16 f2bf(float x){
  unsigned u = __float_as_uint(x);
  return (u16)((u + 0x7FFFu + ((u >> 16) & 1u)) >> 16);   // RNE
}
__device__ __forceinline__ u32 cvtpk(float lo, float hi){
  u32 r; asm("v_cvt_pk_bf16_f32 %0, %1, %2" : "=v"(r) : "v"(lo), "v"(hi)); return r;
}
__device__ __forceinline__ f32x4 mfma16(s16x8 a, s16x8 b, f32x4 c){
  return __builtin_amdgcn_mfma_f32_16x16x32_bf16(a, b, c, 0, 0, 0);
}

// ---------------- kernel 0: weights -> bf16, transposed wt[mat][f][c] ----------------
__global__ void k_wprep(const float* __restrict__ Wq, const float* __restrict__ Wk,
                        const float* __restrict__ Wv, u16* __restrict__ WT){
  int mat = blockIdx.x >> 7;
  int f   = blockIdx.x & 127;
  const float* W = (mat == 0) ? Wq : (mat == 1) ? Wk : Wv;
  int c = threadIdx.x;
  WT[mat * 16384 + f * 128 + c] = f2bf(W[c * 128 + f]);
}

// ---------------- kernel 1: QKV projection (R8-verified layouts) ----------------
// Qs : bf16 [NQ][128], scaled by QK_SCALE (row-major)
// Ks : bf16 [NQ][128], element (r,f) at col f ^ ((r&7)<<3)                 (b128-read swizzle)
// VTs: bf16 [B][128][N], (f,n) at col n ^ ((f&3)<<3) ^ (((f>>2)&1)<<2)     (b64-read swizzle)
__global__ __launch_bounds__(256) void k_proj(
    const float* __restrict__ X, const u16* __restrict__ WT,
    const float* __restrict__ bq, const float* __restrict__ bk, const float* __restrict__ bv,
    u16* __restrict__ Qs, u16* __restrict__ Ks, u16* __restrict__ VTs)
{
  const int lane = threadIdx.x & 63;
  const int w    = threadIdx.x >> 6;
  const int lm = lane & 15, lg = lane >> 4;
  const int rowbase = blockIdx.x * 64 + w * 16;

  s16x8 a[4];
  const float* xr = X + (rowbase + lm) * ND;
  #pragma unroll
  for (int kc = 0; kc < 4; ++kc){
    f32x4 x0 = *(const f32x4*)(xr + kc * 32 + lg * 8);
    f32x4 x1 = *(const f32x4*)(xr + kc * 32 + lg * 8 + 4);
    s16x8 t;
    t[0]=(short)f2bf(x0[0]); t[1]=(short)f2bf(x0[1]); t[2]=(short)f2bf(x0[2]); t[3]=(short)f2bf(x0[3]);
    t[4]=(short)f2bf(x1[0]); t[5]=(short)f2bf(x1[1]); t[6]=(short)f2bf(x1[2]); t[7]=(short)f2bf(x1[3]);
    a[kc] = t;
  }

  #pragma unroll
  for (int mat = 0; mat < 3; ++mat){
    const float* bias = (mat==0) ? bq : (mat==1) ? bk : bv;
    float bl[8];
    #pragma unroll
    for (int n = 0; n < 8; ++n) bl[n] = bias[n * 16 + lm];
    f32x4 acc[8];
    #pragma unroll
    for (int n = 0; n < 8; ++n) acc[n] = f32x4{0.f,0.f,0.f,0.f};
    #pragma unroll
    for (int kc = 0; kc < 4; ++kc){
      #pragma unroll
      for (int n = 0; n < 8; ++n){
        s16x8 bf = *(const s16x8*)&WT[mat*16384 + (n*16 + lm)*128 + kc*32 + lg*8];
        acc[n] = mfma16(a[kc], bf, acc[n]);
      }
    }
    #pragma unroll
    for (int n = 0; n < 8; ++n){
      int f = n * 16 + lm;
      #pragma unroll
      for (int i = 0; i < 4; ++i){
        int r = rowbase + lg * 4 + i;
        float val = acc[n][i] + bl[n];
        if (mat == 0){
          Qs[r * ND + f] = f2bf(val * QK_SCALE);
        } else if (mat == 1){
          Ks[r * ND + (f ^ ((r & 7) << 3))] = f2bf(val);
        } else {
          int bb = r >> 12, nt = r & (NT - 1);
          VTs[(bb * ND + f) * NT + (nt ^ ((f & 3) << 3) ^ (((f >> 2) & 1) << 2))] = f2bf(val);
        }
      }
    }
  }
}

// ---------------- kernel 2: flash attention, 64KB LDS -> 2 blocks/CU ----------
// 512 blocks = 4 kv-quarters (1024 kv) x 128 qblocks (128 q). 8 waves = 4 qw (32 q,
// sq=2) x 2 g (512 kv, 16 tiles of 32). Inner maps identical to R8 (HW-verified).
// In-block merge g1->g0; bf16 partial O + f32 l per quarter; k_merge combines.
__global__ __launch_bounds__(512, 4) void k_attn(
    const u16* __restrict__ Qs, const u16* __restrict__ Ks,
    const u16* __restrict__ VTs, u16* __restrict__ Op, float* __restrict__ lp)
{
  __shared__ __align__(16) u16 lds[32768];          // 64 KiB (staging; reused for merge)
  __shared__ float lbuf[4][32];                     // g1->g0 l merge
  u16* kbuf = lds;                                  // [buf][g][32*128]
  u16* vbuf = lds + 16384;                          // [buf][g][128*32]

  // XCD-chunked: XCD x hosts 64 consecutive logicals (~3MB Q/K/V footprint per L2)
  const int lin = blockIdx.x;
  const int logical = (lin & 7) * 64 + (lin >> 3);
  const int qblk = logical & 127;
  const int quarter = logical >> 7;

  const int lane = threadIdx.x & 63;
  const int w  = threadIdx.x >> 6;
  const int qw = w >> 1, g = w & 1;                 // 4 q-waves, 2 kv-groups
  const int lm = lane & 15, lg = lane >> 4;
  const int q0 = qblk * 128 + qw * 32;              // global q base for this wave
  const int b  = q0 >> 12;                          // batch
  const int kv0 = quarter * 1024 + g * 512;

  // Q frags in registers: rows q0 + sq*16 + lm, k = kc*32 + lg*8 + j  (R8 map)
  s16x8 aq[2][4];
  #pragma unroll
  for (int sq = 0; sq < 2; ++sq){
    const u16* qr = Qs + (size_t)(q0 + sq * 16 + lm) * ND;
    #pragma unroll
    for (int kc = 0; kc < 4; ++kc) aq[sq][kc] = *(const s16x8*)(qr + kc * 32 + lg * 8);
  }

  f32x4 o[2][8];
  #pragma unroll
  for (int sq = 0; sq < 2; ++sq)
    #pragma unroll
    for (int n = 0; n < 8; ++n) o[sq][n] = f32x4{0.f,0.f,0.f,0.f};
  float l_[2] = {0.f, 0.f};

  // staging: 4 qw waves split each group's tile; this wave: 2 K + 2 V chunks (1KB each)
  const u16* gk = Ks  + ((size_t)b * NT + kv0 + qw * 8 + (lane >> 4)) * ND + (lane & 15) * 8;
  const u16* gv = VTs + ((size_t)b * ND + qw * 32 + (lane >> 2)) * NT + kv0 + (lane & 3) * 8;

  auto stage = [&](int buf){
    u16* kd = kbuf + (buf * 2 + g) * 4096 + qw * 1024;
    u16* vd = vbuf + (buf * 2 + g) * 4096 + qw * 1024;
    __builtin_amdgcn_global_load_lds((const as1_void*)gk,
                                     (as3_void*)kd, 16, 0, 0);
    __builtin_amdgcn_global_load_lds((const as1_void*)(gk + (size_t)4 * ND),
                                     (as3_void*)(kd + 512), 16, 0, 0);
    __builtin_amdgcn_global_load_lds((const as1_void*)gv,
                                     (as3_void*)vd, 16, 0, 0);
    __builtin_amdgcn_global_load_lds((const as1_void*)(gv + (size_t)16 * NT),
                                     (as3_void*)(vd + 512), 16, 0, 0);
    gk += (size_t)32 * ND;
    gv += 32;
  };

  const int kswz = (lm & 7) << 3;                           // K b128-read swizzle
  const int vswz = ((lm & 3) << 3) ^ (((lm >> 2) & 1) << 2);// V b64-read swizzle
  const int vcol0 = (lg * 4) ^ vswz;                        // kv lg*4 + {0..3}
  const int vcol1 = (16 + lg * 4) ^ vswz;                   // kv 16+lg*4 + {0..3}

  stage(0);
  __syncthreads();
  int par = 0;

  for (int t = 0; t < 16; ++t){
    if (t < 15) stage(par ^ 1);                 // prefetch next tile
    const u16* kb = kbuf + (par * 2 + g) * 4096;
    const u16* vb = vbuf + (par * 2 + g) * 4096;

    // ---- S^T = K Q : swapped operands; kf shared across sq ----
    f32x4 st[2][2];
    #pragma unroll
    for (int sq = 0; sq < 2; ++sq)
      #pragma unroll
      for (int n = 0; n < 2; ++n) st[sq][n] = f32x4{0.f,0.f,0.f,0.f};
    __builtin_amdgcn_s_setprio(1);
    #pragma unroll
    for (int kc = 0; kc < 4; ++kc){
      #pragma unroll
      for (int n = 0; n < 2; ++n){
        s16x8 kf = *(const s16x8*)&kb[(n * 16 + lm) * 128 + ((kc * 32 + lg * 8) ^ kswz)];
        st[0][n] = mfma16(kf, aq[0][kc], st[0][n]);
        st[1][n] = mfma16(kf, aq[1][kc], st[1][n]);
      }
    }
    __builtin_amdgcn_s_setprio(0);

    // ---- fixed-ref softmax in registers; pack PV A-frags (R8 bijection) ----
    s16x8 pa[2];
    #pragma unroll
    for (int sq = 0; sq < 2; ++sq){
      float p[8];
      #pragma unroll
      for (int n = 0; n < 2; ++n)
        #pragma unroll
        for (int i = 0; i < 4; ++i){
          p[n * 4 + i] = __builtin_amdgcn_exp2f(st[sq][n][i]);
          l_[sq] += p[n * 4 + i];
        }
      pa[sq] = __builtin_bit_cast(s16x8, u32x4{
          cvtpk(p[0], p[1]), cvtpk(p[2], p[3]),
          cvtpk(p[4], p[5]), cvtpk(p[6], p[7])});
    }

    // ---- O += P V : vf = 2x b64 (R8 map); shared across sq ----
    __builtin_amdgcn_s_setprio(1);
    #pragma unroll
    for (int nf = 0; nf < 8; ++nf){
      const int vr = (nf * 16 + lm) * 32;
      u32x2 v0 = *(const u32x2*)&vb[vr + vcol0];
      u32x2 v1 = *(const u32x2*)&vb[vr + vcol1];
      s16x8 vf = __builtin_bit_cast(s16x8, u32x4{v0[0], v0[1], v1[0], v1[1]});
      o[0][nf] = mfma16(pa[0], vf, o[0][nf]);
      o[1][nf] = mfma16(pa[1], vf, o[1][nf]);
    }
    __builtin_amdgcn_s_setprio(0);

    __syncthreads();   // drains prefetch vmcnt + releases buf[par]
    par ^= 1;
  }

  // ---- l: reduce over lg (lanes sharing q) ----
  #pragma unroll
  for (int sq = 0; sq < 2; ++sq){
    float v = l_[sq];
    v += __shfl_xor(v, 16);
    v += __shfl_xor(v, 32);
    l_[sq] = v;                       // all lanes: l for q = sq*16+lm (this g)
  }

  // ---- merge g1 -> g0 via LDS; write bf16 partials for this quarter ----
  float* mbF = (float*)lds;           // [4 qw][32 q][128 f] f32 = 64 KiB (reuse)
  __syncthreads();
  if (g == 1){
    #pragma unroll
    for (int sq = 0; sq < 2; ++sq){
      #pragma unroll
      for (int i = 0; i < 4; ++i)
        #pragma unroll
        for (int nf = 0; nf < 8; ++nf)
          mbF[qw * 4096 + (sq * 16 + lg * 4 + i) * 128 + nf * 16 + lm] = o[sq][nf][i];
      if (lg == 0) lbuf[qw][sq * 16 + lm] = l_[sq];
    }
  }
  __syncthreads();
  if (g == 0){
    #pragma unroll
    for (int sq = 0; sq < 2; ++sq){
      l_[sq] += lbuf[qw][sq * 16 + lm];
      #pragma unroll
      for (int i = 0; i < 4; ++i){
        const size_t r = (size_t)quarter * NQ + q0 + sq * 16 + lg * 4 + i;
        #pragma unroll
        for (int nf = 0; nf < 8; ++nf)
          Op[r * ND + nf * 16 + lm] = f2bf(
              o[sq][nf][i] + mbF[qw * 4096 + (sq * 16 + lg * 4 + i) * 128 + nf * 16 + lm]);
      }
      if (lg == 0) lp[(size_t)quarter * NQ + q0 + sq * 16 + lm] = l_[sq];
    }
  }
}

// ---------------- kernel 3: merge 4 kv-quarters + normalize ----------------
__global__ __launch_bounds__(256) void k_merge(const u16* __restrict__ Op,
                                               const float* __restrict__ lp,
                                               float* __restrict__ Out){
  const int gid = blockIdx.x * 256 + threadIdx.x;   // over NQ*16 8-wide chunks
  const int q = gid >> 4, c = gid & 15;
  const float inv = 1.f / (lp[q] + lp[NQ + q] + lp[2 * NQ + q] + lp[3 * NQ + q]);
  float acc[8] = {0,0,0,0,0,0,0,0};
  #pragma unroll
  for (int qt = 0; qt < 4; ++qt){
    s16x8 v = *(const s16x8*)(Op + ((size_t)qt * NQ + q) * ND + c * 8);
    #pragma unroll
    for (int j = 0; j < 8; ++j)
      acc[j] += __uint_as_float(((u32)(u16)v[j]) << 16);
  }
  f32x4 r0{acc[0]*inv, acc[1]*inv, acc[2]*inv, acc[3]*inv};
  f32x4 r1{acc[4]*inv, acc[5]*inv, acc[6]*inv, acc[7]*inv};
  *(f32x4*)(Out + (size_t)q * ND + c * 8)     = r0;
  *(f32x4*)(Out + (size_t)q * ND + c * 8 + 4) = r1;
}

extern "C" void kernel_launch(void* const* d_in, const int* in_sizes, int n_in,
                              void* d_out, int out_size, void* d_ws, size_t ws_size,
                              hipStream_t stream) {
  const float* X  = (const float*)d_in[0];
  const float* Wq = (const float*)d_in[1];
  const float* bq = (const float*)d_in[2];
  const float* Wk = (const float*)d_in[3];
  const float* bk = (const float*)d_in[4];
  const float* Wv = (const float*)d_in[5];
  const float* bv = (const float*)d_in[6];
  float* Out = (float*)d_out;

  u16* Qs  = (u16*)d_ws;                        // 4 MiB
  u16* Ks  = Qs  + (size_t)NQ * ND;             // 4 MiB
  u16* VTs = Ks  + (size_t)NQ * ND;             // 4 MiB
  u16* WT  = VTs + (size_t)NQ * ND;             // 96 KiB
  u16* Op  = WT + 3 * 128 * 128;                // 16 MiB (4 quarters, bf16)
  float* lp = (float*)(Op + (size_t)4 * NQ * ND);  // 256 KiB

  hipLaunchKernelGGL(k_wprep, dim3(3 * 128), dim3(128), 0, stream, Wq, Wk, Wv, WT);
  hipLaunchKernelGGL(k_proj,  dim3(NQ / 64), dim3(256), 0, stream,
                     X, WT, bq, bk, bv, Qs, Ks, VTs);
  hipLaunchKernelGGL(k_attn,  dim3(512), dim3(512), 0, stream, Qs, Ks, VTs, Op, lp);
  hipLaunchKernelGGL(k_merge, dim3(NQ * 16 / 256), dim3(256), 0, stream, Op, lp, Out);
}